// Round 15
// baseline (686.963 us; speedup 1.0000x reference)
//
#include <hip/hip_runtime.h>

#define RNN_B 256
#define RNN_T 2048
#define RNN_IN 64
#define RNN_N 32
#define RNN_O 32
#define RNN_R 6
#define RNN_ALPHA 0.1f
#define KSCALE 2.8853900817779268f   /* 2*log2(e): folded into cm and xp */

// ---------------------------------------------------------------------------
// Kernel 1: xp[row][n] = KSCALE * (bias[n] + sum_i W_in[n][i] * u[row][i])
// (R13 LDS-staged version, unchanged; destination is now the workspace.)
// ---------------------------------------------------------------------------
__global__ __launch_bounds__(256) void k_xproj(
    const float* __restrict__ u, const float* __restrict__ W_in,
    const float* __restrict__ bias, float* __restrict__ xp)
{
    __shared__ float4 lds[4096];                 // 64 KB, dual-purpose
    const int tid = threadIdx.x;
    const size_t row0 = (size_t)blockIdx.x * 256;

    const float4* __restrict__ u4 =
        reinterpret_cast<const float4*>(u) + row0 * (RNN_IN / 4);
    #pragma unroll
    for (int j = 0; j < 16; ++j) {
        const int g   = tid + j * 256;           // 0..4095
        const int row = g >> 4, q = g & 15;
        lds[row * 16 + (q ^ (row & 15))] = u4[g];
    }
    __syncthreads();

    float acc[RNN_N];
    #pragma unroll
    for (int n = 0; n < RNN_N; ++n) acc[n] = bias[n];
    const int sw = tid & 15;
    #pragma unroll
    for (int qq = 0; qq < RNN_IN / 4; ++qq) {
        const float4 v = lds[tid * 16 + (qq ^ sw)];
        #pragma unroll
        for (int n = 0; n < RNN_N; ++n) {
            const float* wr = W_in + n * RNN_IN + 4 * qq;   // uniform -> s_load
            acc[n] = fmaf(wr[0], v.x, acc[n]);
            acc[n] = fmaf(wr[1], v.y, acc[n]);
            acc[n] = fmaf(wr[2], v.z, acc[n]);
            acc[n] = fmaf(wr[3], v.w, acc[n]);
        }
    }
    __syncthreads();

    const int sw8 = tid & 7;
    #pragma unroll
    for (int q = 0; q < RNN_N / 4; ++q)
        lds[tid * 8 + (q ^ sw8)] =
            make_float4(KSCALE * acc[4*q+0], KSCALE * acc[4*q+1],
                        KSCALE * acc[4*q+2], KSCALE * acc[4*q+3]);
    __syncthreads();

    float4* __restrict__ o4 =
        reinterpret_cast<float4*>(xp) + row0 * (RNN_N / 4);
    #pragma unroll
    for (int j = 0; j < 8; ++j) {
        const int g   = tid + j * 256;
        const int row = g >> 3, q = g & 7;
        o4[g] = lds[row * 8 + (q ^ (row & 7))];
    }
}

// ---------------------------------------------------------------------------
// Cross-lane helpers: all-VALU (DPP / permlane), no LDS pipe.
// ---------------------------------------------------------------------------
template <int CTRL>
__device__ __forceinline__ float dpp_add(float v) {
    int t = __builtin_amdgcn_update_dpp(0, __float_as_int(v), CTRL, 0xf, 0xf, true);
    return v + __int_as_float(t);
}
__device__ __forceinline__ float xsum32(float v) {
#if __has_builtin(__builtin_amdgcn_permlane32_swap)
    typedef int v2i __attribute__((ext_vector_type(2)));
    v2i r = __builtin_amdgcn_permlane32_swap(__float_as_int(v),
                                             __float_as_int(v), false, false);
    return __int_as_float(r.x) + __int_as_float(r.y);
#else
    return v + __shfl_xor(v, 32, 64);
#endif
}
__device__ __forceinline__ float xsum16(float v) {
#if __has_builtin(__builtin_amdgcn_permlane16_swap)
    typedef int v2i __attribute__((ext_vector_type(2)));
    v2i r = __builtin_amdgcn_permlane16_swap(__float_as_int(v),
                                             __float_as_int(v), false, false);
    return __int_as_float(r.x) + __int_as_float(r.y);
#else
    return v + __shfl_xor(v, 16, 64);
#endif
}
__device__ __forceinline__ float fast_exp2(float x) {
#if __has_builtin(__builtin_amdgcn_exp2f)
    return __builtin_amdgcn_exp2f(x);
#else
    return __expf(x * 0.6931471805599453f);
#endif
}
__device__ __forceinline__ float fast_rcp(float x) {
#if __has_builtin(__builtin_amdgcn_rcpf)
    return __builtin_amdgcn_rcpf(x);
#else
    return __frcp_rn(x);
#endif
}

// ---------------------------------------------------------------------------
// Kernel 2: scan + FUSED output projection. One wave per batch.
// Scan core is the measured-310us R5 version, untouched: 2x2 lane decomp
// (k=lane&15, q=rank group, p=parity; lane owns element e=2k+p).
// NEW: h(t) goes to a tiny double-buffered LDS slab (no global h at all);
// while step t+1's recurrence chain runs, the wave computes
// y(t) = b_out + W_out·h(t) — work that is INDEPENDENT of the serial
// fold->exp2->rcp chain and thus fills its ~128 exposed-latency cycles.
// y-lane mapping: o = lane&31, z = lane>>5 (half of the dot product);
// 4 broadcast ds_read_b128 + 16 FMA + permlane32 combine + 128B store.
// y writes go to 'out' while xp reads come from 'ws' (distinct streams).
// ---------------------------------------------------------------------------
__global__ __launch_bounds__(64, 1) void k_recur(
    const float* __restrict__ m, const float* __restrict__ nvec,
    const float* __restrict__ Mmat, const float* __restrict__ Nmat,
    const float* __restrict__ W_out, const float* __restrict__ b_out,
    const float* __restrict__ xp,    // [B,T,N] prescaled input projections
    float* __restrict__ yout,        // [B,T,N] outputs
    float* __restrict__ hfin)
{
    __shared__ float hbuf[2][RNN_N];     // 256 B double buffer, 1 wave: no bar
    const int b    = blockIdx.x;
    const int lane = threadIdx.x;
    const int k    = lane & 15;
    const int q    = (lane >> 4) & 1;    // rank group: 0 -> r 0..3, 1 -> r 4..6
    const int p    = lane >> 5;          // element parity
    const int e    = 2 * k + p;          // my hidden element

    // Scan coefficients (unchanged).
    float cn[4], cm[4];
    #pragma unroll
    for (int j = 0; j < 4; ++j) {
        const int r = 4 * q + j;
        float cnv = 0.f, cmv = 0.f;
        if (r == 0)          { cnv = nvec[e];               cmv = m[e]; }
        else if (r <= RNN_R) { cnv = Nmat[e*RNN_R + (r-1)]; cmv = Mmat[e*RNN_R + (r-1)]; }
        cn[j] = cnv;
        cm[j] = KSCALE * cmv;
    }

    // y coefficients: lane (o, z) holds W_out[o][16z..16z+15] and half-bias.
    const int o = lane & 31;
    const int z = p;
    float4 wo0, wo1, wo2, wo3;
    {
        const float4* wrow =
            reinterpret_cast<const float4*>(W_out + o * RNN_N + 16 * z);
        wo0 = wrow[0]; wo1 = wrow[1]; wo2 = wrow[2]; wo3 = wrow[3];
    }
    const float ybias = (z == 0) ? b_out[o] : 0.0f;

    const float2* __restrict__ x2 =
        reinterpret_cast<const float2*>(xp + (size_t)b * (RNN_T * RNN_N)) + k;
    float* __restrict__ ybase = yout + (size_t)b * (RNN_T * RNN_N);

    float h = 0.0f;
    // Init both LDS buffers (iter-0 y math reads garbage otherwise; result
    // is discarded via the t>=1 store guard, but keep values finite).
    if (q == 0) { hbuf[0][e] = 0.f; hbuf[1][e] = 0.f; }

    const int PF = 8;
    float2 xr[PF];
    #pragma unroll
    for (int i = 0; i < PF; ++i) xr[i] = x2[i * (RNN_N / 2)];

    const bool hwrite = (q == 0);        // 32 lanes cover e = 0..31
    const bool ystore = (p == 0);        // 32 lanes cover o = 0..31

    #pragma unroll 8
    for (int t = 0; t < RNN_T; ++t) {
        const int slot = t & (PF - 1);
        const float2 xv = xr[slot];
        xr[slot] = x2[(t + PF) * (RNN_N / 2)];   // past-T lands in hfin tail
        const float xe = p ? xv.y : xv.x;

        // Issue the y(t-1) LDS reads early (data ready since last iter).
        const float4* hprev =
            reinterpret_cast<const float4*>(&hbuf[(t + 1) & 1][16 * z]);
        const float4 a0 = hprev[0], a1 = hprev[1],
                     a2 = hprev[2], a3 = hprev[3];

        // ---- scan core (unchanged) ----
        float s0 = cn[0] * h, s1 = cn[1] * h, s2 = cn[2] * h, s3 = cn[3] * h;
        s0 = dpp_add<0xB1>(s0);  s1 = dpp_add<0xB1>(s1);
        s2 = dpp_add<0xB1>(s2);  s3 = dpp_add<0xB1>(s3);
        s0 = dpp_add<0x4E>(s0);  s1 = dpp_add<0x4E>(s1);
        s2 = dpp_add<0x4E>(s2);  s3 = dpp_add<0x4E>(s3);
        s0 = dpp_add<0x141>(s0); s1 = dpp_add<0x141>(s1);
        s2 = dpp_add<0x141>(s2); s3 = dpp_add<0x141>(s3);
        s0 = dpp_add<0x140>(s0); s1 = dpp_add<0x140>(s1);
        s2 = dpp_add<0x140>(s2); s3 = dpp_add<0x140>(s3);

        s0 = xsum32(s0); s1 = xsum32(s1); s2 = xsum32(s2); s3 = xsum32(s3);

        float w = fmaf(cm[1], s1, cm[0] * s0) + fmaf(cm[3], s3, cm[2] * s2);
        w = xsum16(w);
        const float zz = w + xe;

        const float ez = fast_exp2(zz);
        const float g  = fmaf(1.0f - RNN_ALPHA, h, RNN_ALPHA);
        h = fmaf(-2.0f * RNN_ALPHA, fast_rcp(ez + 1.0f), g);

        // Stash h(t) for next iteration's y pass.
        if (hwrite) hbuf[t & 1][e] = h;

        // ---- fused y(t-1): independent of the recurrence chain ----
        float yp = ybias;
        yp = fmaf(wo0.x, a0.x, yp); yp = fmaf(wo0.y, a0.y, yp);
        yp = fmaf(wo0.z, a0.z, yp); yp = fmaf(wo0.w, a0.w, yp);
        yp = fmaf(wo1.x, a1.x, yp); yp = fmaf(wo1.y, a1.y, yp);
        yp = fmaf(wo1.z, a1.z, yp); yp = fmaf(wo1.w, a1.w, yp);
        yp = fmaf(wo2.x, a2.x, yp); yp = fmaf(wo2.y, a2.y, yp);
        yp = fmaf(wo2.z, a2.z, yp); yp = fmaf(wo2.w, a2.w, yp);
        yp = fmaf(wo3.x, a3.x, yp); yp = fmaf(wo3.y, a3.y, yp);
        yp = fmaf(wo3.z, a3.z, yp); yp = fmaf(wo3.w, a3.w, yp);
        const float yv = xsum32(yp);             // combine the two 16-halves
        if (t >= 1 && ystore) ybase[(size_t)(t - 1) * RNN_N + o] = yv;
    }

    // Epilogue: y(T-1) from hbuf[(T-1)&1] = hbuf[1].
    {
        const float4* hprev =
            reinterpret_cast<const float4*>(&hbuf[(RNN_T - 1) & 1][16 * z]);
        const float4 a0 = hprev[0], a1 = hprev[1],
                     a2 = hprev[2], a3 = hprev[3];
        float yp = ybias;
        yp = fmaf(wo0.x, a0.x, yp); yp = fmaf(wo0.y, a0.y, yp);
        yp = fmaf(wo0.z, a0.z, yp); yp = fmaf(wo0.w, a0.w, yp);
        yp = fmaf(wo1.x, a1.x, yp); yp = fmaf(wo1.y, a1.y, yp);
        yp = fmaf(wo1.z, a1.z, yp); yp = fmaf(wo1.w, a1.w, yp);
        yp = fmaf(wo2.x, a2.x, yp); yp = fmaf(wo2.y, a2.y, yp);
        yp = fmaf(wo2.z, a2.z, yp); yp = fmaf(wo2.w, a2.w, yp);
        yp = fmaf(wo3.x, a3.x, yp); yp = fmaf(wo3.y, a3.y, yp);
        yp = fmaf(wo3.z, a3.z, yp); yp = fmaf(wo3.w, a3.w, yp);
        const float yv = xsum32(yp);
        if (ystore) ybase[(size_t)(RNN_T - 1) * RNN_N + o] = yv;
    }

    if (hwrite) hfin[b * RNN_N + e] = h;
}

extern "C" void kernel_launch(void* const* d_in, const int* in_sizes, int n_in,
                              void* d_out, int out_size, void* d_ws, size_t ws_size,
                              hipStream_t stream)
{
    const float* u     = (const float*)d_in[0];  // [256,2048,64]
    const float* W_in  = (const float*)d_in[1];  // [32,64]
    const float* m     = (const float*)d_in[2];  // [32,1]
    const float* nvec  = (const float*)d_in[3];  // [32,1]
    const float* Mmat  = (const float*)d_in[4];  // [32,6]
    const float* Nmat  = (const float*)d_in[5];  // [32,6]
    const float* bias  = (const float*)d_in[6];  // [32]
    const float* W_out = (const float*)d_in[7];  // [32,32]
    const float* b_out = (const float*)d_in[8];  // [32]
    float* out = (float*)d_out;                  // outputs [256,2048,32] ++ h_final [256,32]

    float* hfin = out + (size_t)RNN_B * RNN_T * RNN_N;

    // xp lives in the workspace; y goes straight to out (distinct streams).
    // Fallback (ws too small): xp in out, overwritten in place by y — safe,
    // since y(t-1) is written only after xp rows <= t+7 are consumed and the
    // write trails all outstanding prefetch rows.
    const size_t xpbytes = (size_t)RNN_B * RNN_T * RNN_N * sizeof(float);
    float* xpbuf = (ws_size >= xpbytes) ? (float*)d_ws : out;

    k_xproj<<<(RNN_B * RNN_T) / 256, 256, 0, stream>>>(u, W_in, bias, xpbuf);
    k_recur<<<RNN_B, 64, 0, stream>>>(m, nvec, Mmat, Nmat, W_out, b_out,
                                      xpbuf, out, hfin);
}